// Round 4
// baseline (289.366 us; speedup 1.0000x reference)
//
#include <hip/hip_runtime.h>
#include <math.h>
#include <utility>

// B=16, T=16, FDIM=64, ODIM=8, NQ=10, NA=4, LAYERS=2, DEGREE=3.
// Single kernel, 256 blocks x 64 threads (1 wave/block). Block blk = b*16+aa
// owns column (b, aa): 1024 amplitudes register-resident, n = lane*16 + r
// (bits [3:0]=r in-thread, [9:4]=lane). Gates on n-bit<4: thread-local;
// n-bit>=4: __shfl_xor butterfly. Cross-column steps use a software grid
// barrier (256 single-wave blocks on 256 CUs are always co-resident:
// 256 waves << 8192 wave slots).

struct Gate { int ry; int tbit; int cbit; int pidx; };
struct GateTab { Gate g[40]; };

constexpr GateTab make_gates1() {
  GateTab tb{};
  int pos = 0, idx = 0;
  for (int i = 0; i < 10; ++i) { tb.g[pos] = Gate{1, 9 - i, -1, idx}; ++pos; ++idx; }
  for (int i = 9; i >= 0; --i) { tb.g[pos] = Gate{0, 9 - ((i + 1) % 10), 9 - i, idx}; ++pos; ++idx; }
  for (int i = 0; i < 10; ++i) { tb.g[pos] = Gate{1, 9 - i, -1, idx}; ++pos; ++idx; }
  for (int k = 0; k < 10; ++k) {
    int i = (k == 0) ? 9 : (k - 1);
    tb.g[pos] = Gate{0, 9 - ((i + 9) % 10), 9 - i, idx}; ++pos; ++idx;
  }
  return tb;
}
constexpr GateTab GTC = make_gates1();

__device__ __forceinline__ int insert_zero(int v, int p) {
  return ((v >> p) << (p + 1)) | (v & ((1 << p) - 1));
}
__device__ __forceinline__ float2 cmul(float2 A, float2 B) {
  return make_float2(A.x * B.x - A.y * B.y, A.x * B.y + A.y * B.x);
}
__device__ __forceinline__ float2 conj2(float2 A) { return make_float2(A.x, -A.y); }
__device__ __forceinline__ float2 cfma(float2 A, float2 B, float2 acc) {
  acc.x += A.x * B.x - A.y * B.y;
  acc.y += A.x * B.y + A.y * B.x;
  return acc;
}

// Software grid barrier: lane0 arrives + spins; single-wave block => lockstep
// reconvergence covers the other lanes. threadfence = agent-scope fence
// (emits L2 writeback/invalidate on gfx950 for cross-XCD visibility).
__device__ __forceinline__ void grid_barrier(int* cnt, int target, int lane) {
  __threadfence();                                   // release my stores
  if (lane == 0) {
    __hip_atomic_fetch_add(cnt, 1, __ATOMIC_ACQ_REL, __HIP_MEMORY_SCOPE_AGENT);
    while (__hip_atomic_load(cnt, __ATOMIC_ACQUIRE, __HIP_MEMORY_SCOPE_AGENT) < target)
      __builtin_amdgcn_s_sleep(2);
  }
  __threadfence();                                   // acquire others' stores
}

// ---------------- register/shuffle gate engine ----------------
template<int P>
__device__ __forceinline__ void ry_gate(float2 (&a)[16], float c, float s, int lane) {
  if constexpr (P < 4) {
    constexpr int m = 1 << P;
#pragma unroll
    for (int r0 = 0; r0 < 16; ++r0) {
      if (!(r0 & m)) {
        int r1 = r0 | m;
        float2 a0 = a[r0], a1 = a[r1];
        a[r0] = make_float2(c * a0.x - s * a1.x, c * a0.y - s * a1.y);
        a[r1] = make_float2(s * a0.x + c * a1.x, s * a0.y + c * a1.y);
      }
    }
  } else {
    constexpr int xm = 1 << (P - 4);
    bool up = (lane >> (P - 4)) & 1;
    float sg = up ? s : -s;
#pragma unroll
    for (int r = 0; r < 16; ++r) {
      float wx = __shfl_xor(a[r].x, xm, 64);
      float wy = __shfl_xor(a[r].y, xm, 64);
      a[r].x = c * a[r].x + sg * wx;
      a[r].y = c * a[r].y + sg * wy;
    }
  }
}

template<int P, int Q>
__device__ __forceinline__ void crx_gate(float2 (&a)[16], float c, float s, int lane) {
  if constexpr (P < 4) {
    constexpr int m = 1 << P;
#pragma unroll
    for (int r0 = 0; r0 < 16; ++r0) {
      if (!(r0 & m)) {
        int r1 = r0 | m;
        bool act;
        if constexpr (Q < 4) act = (r0 >> Q) & 1;
        else act = (lane >> (Q - 4)) & 1;
        if (act) {
          float2 a0 = a[r0], a1 = a[r1];
          a[r0] = make_float2(c * a0.x + s * a1.y, c * a0.y - s * a1.x);
          a[r1] = make_float2(c * a1.x + s * a0.y, c * a1.y - s * a0.x);
        }
      }
    }
  } else {
    constexpr int xm = 1 << (P - 4);
#pragma unroll
    for (int r = 0; r < 16; ++r) {
      float wx = __shfl_xor(a[r].x, xm, 64);
      float wy = __shfl_xor(a[r].y, xm, 64);
      bool act;
      if constexpr (Q < 4) act = (r >> Q) & 1;
      else act = (lane >> (Q - 4)) & 1;
      if (act) {
        float nx = c * a[r].x + s * wy;
        float ny = c * a[r].y - s * wx;
        a[r].x = nx; a[r].y = ny;
      }
    }
  }
}

template<bool ADJ, int G>
__device__ __forceinline__ void one_gate(float2 (&a)[16], const float2* sc, int lane) {
  constexpr Gate g = GTC.g[ADJ ? (39 - G) : G];
  float2 scv = sc[g.pidx];          // (sin(th/2), cos(th/2)), wave-uniform LDS read
  float s = ADJ ? -scv.x : scv.x;
  float c = scv.y;
  if constexpr (g.ry != 0) ry_gate<g.tbit>(a, c, s, lane);
  else crx_gate<g.tbit, g.cbit>(a, c, s, lane);
}

template<bool ADJ, int... I>
__device__ __forceinline__ void run_layer_impl(float2 (&a)[16], const float2* sc,
                                               int lane, std::integer_sequence<int, I...>) {
  (one_gate<ADJ, I>(a, sc, lane), ...);
}
template<bool ADJ>
__device__ __forceinline__ void run_layer(float2 (&a)[16], const float2* sc, int lane) {
  run_layer_impl<ADJ>(a, sc, lane, std::make_integer_sequence<int, 40>{});
}

// a[r] = sum_ap Mrow[ap] * src[b][ap][lane*16+r]   (Mrow in LDS)
__device__ __forceinline__ void mix_load(float2 (&a)[16], const float2* __restrict__ src,
                                         const float2* Mrow, int b, int lane) {
#pragma unroll
  for (int r = 0; r < 16; ++r) a[r] = make_float2(0.f, 0.f);
#pragma unroll
  for (int ap = 0; ap < 16; ++ap) {
    float2 m = Mrow[ap];
    const float4* col4 = (const float4*)(src + (size_t)(b * 16 + ap) * 1024) + lane * 8;
#pragma unroll
    for (int q = 0; q < 8; ++q) {
      float4 v = col4[q];
      a[2 * q].x     += m.x * v.x - m.y * v.y;
      a[2 * q].y     += m.x * v.y + m.y * v.x;
      a[2 * q + 1].x += m.x * v.z - m.y * v.w;
      a[2 * q + 1].y += m.x * v.w + m.y * v.z;
    }
  }
}

__global__ __launch_bounds__(64)
void k_all(const float* __restrict__ x, const float* __restrict__ W_fp,
           const float* __restrict__ b_fp, const float* __restrict__ prep,
           const float* __restrict__ sig, const float* __restrict__ qff,
           const float* __restrict__ W_out, const float* __restrict__ b_out,
           float2* __restrict__ state0, float2* __restrict__ state1,
           float* __restrict__ sv, int* __restrict__ bar,
           float* __restrict__ out) {
  int blk = blockIdx.x, lane = threadIdx.x;   // blk = b*16 + aa
  int b = blk >> 4, aa = blk & 15;

  __shared__ __align__(16) float h[64];
  __shared__ float2 th_sc[80];
  __shared__ float2 qsc[40];
  __shared__ float2 psc[32];
  __shared__ float2 esc[4];       // e^{i sig[k]} as (re, im)
  __shared__ float2 U[256];       // U[row*16 + col]
  __shared__ float2 m1row[16], m2row[16], merow[16];

  // ---- phase 0: block-local precompute ----
  {
    int k = lane >> 1;
    float div = expf(-(float)(2 * k) * (logf(10000.f) / 64.f));
    float ang = (float)aa * div;
    float pe = (lane & 1) ? cosf(ang) : sinf(ang);
    h[lane] = x[(b * 64 + lane) * 16 + aa] + pe;
  }
  if (lane < 40) {
    float s, c;
    sincosf(0.5f * qff[lane], &s, &c);
    qsc[lane] = make_float2(s, c);
  }
  if (lane < 32) {
    float s, c;
    sincosf(0.5f * prep[lane], &s, &c);
    psc[lane] = make_float2(s, c);
  }
  if (lane < 4) {
    float s, c;
    sincosf(sig[lane], &s, &c);
    esc[lane] = make_float2(c, s);
  }
#pragma unroll
  for (int i = lane; i < 256; i += 64)
    U[i] = make_float2((i >> 4) == (i & 15) ? 1.f : 0.f, 0.f);
  __syncthreads();

  // feature-map angles for this column (t = aa)
  for (int r = lane; r < 80; r += 64) {
    float acc = b_fp[r];
    const float4* w4 = (const float4*)(W_fp + r * 64);
    const float4* h4 = (const float4*)h;
#pragma unroll
    for (int q = 0; q < 16; ++q) {
      float4 wv = w4[q];
      float4 hv = h4[q];
      acc += hv.x * wv.x + hv.y * wv.y + hv.z * wv.z + hv.w * wv.w;
    }
    float sg = 1.f / (1.f + expf(-acc));
    float s, c;
    sincosf(sg * 3.14159265358979323846f, &s, &c);   // theta/2
    th_sc[r] = make_float2(s, c);
  }

  // build U_prep (16x16) in LDS, single wave
  for (int ly = 0; ly < 4; ++ly) {
    for (int qi = 0; qi < 4; ++qi) {
      int p = 3 - qi;
      {
        float2 sc = psc[ly * 8 + qi * 2 + 0];
        float s = sc.x, c = sc.y;
#pragma unroll
        for (int u = 0; u < 2; ++u) {
          int idx = lane + 64 * u;
          int j = idx & 15, pp = idx >> 4;
          int a0 = insert_zero(pp, p), a1 = a0 | (1 << p);
          float2 u0 = U[a0 * 16 + j], u1 = U[a1 * 16 + j];
          U[a0 * 16 + j] = make_float2(c * u0.x - s * u1.x, c * u0.y - s * u1.y);
          U[a1 * 16 + j] = make_float2(s * u0.x + c * u1.x, s * u0.y + c * u1.y);
        }
      }
      __syncthreads();
      {
        float2 sc = psc[ly * 8 + qi * 2 + 1];
        float s = sc.x, c = sc.y;
#pragma unroll
        for (int u = 0; u < 2; ++u) {
          int idx = lane + 64 * u;
          int j = idx & 15, pp = idx >> 4;
          int a0 = insert_zero(pp, p), a1 = a0 | (1 << p);
          float2 u0 = U[a0 * 16 + j], u1 = U[a1 * 16 + j];
          U[a0 * 16 + j] = make_float2(c * u0.x + s * u0.y, c * u0.y - s * u0.x);
          U[a1 * 16 + j] = make_float2(c * u1.x - s * u1.y, c * u1.y + s * u1.x);
        }
      }
      __syncthreads();
    }
    for (int i = 0; i < 3; ++i) {
      int pc = 3 - i, pt = 2 - i;
      {
        int j = lane & 15, pp = lane >> 4;
        int m = insert_zero(pp, pt);
        m = insert_zero(m, pc);
        int a0 = m | (1 << pc), a1 = a0 | (1 << pt);
        float2 t0 = U[a0 * 16 + j], t1 = U[a1 * 16 + j];
        U[a0 * 16 + j] = t1;
        U[a1 * 16 + j] = t0;
      }
      __syncthreads();
    }
  }

  // extract row aa of M1 = U D1 U^dag, M2 = U D2 U^dag, Mend = D3 U^dag
  if (lane < 16) {
    int ap = lane;
    float2 e1 = esc[1], e2 = esc[2], e3 = esc[3];
    float2 acc1 = make_float2(0.f, 0.f), acc2 = make_float2(0.f, 0.f);
    for (int c = 0; c < 16; ++c) {
      float2 t = cmul(U[aa * 16 + c], conj2(U[ap * 16 + c]));
      acc1 = cfma(t, (c == 0) ? e1 : conj2(e1), acc1);
      acc2 = cfma(t, (c == 0) ? e2 : conj2(e2), acc2);
    }
    m1row[ap] = acc1;
    m2row[ap] = acc2;
    float2 v3 = (aa == 0) ? e3 : conj2(e3);
    merow[ap] = cmul(v3, conj2(U[ap * 16 + aa]));
  }
  __syncthreads();

  // ---- phase A: init |0> -> prepare column aa, select forward ----
  float2 a[16];
#pragma unroll
  for (int r = 0; r < 16; ++r) a[r] = make_float2(0.f, 0.f);
  if (lane == 0) a[0] = cmul(U[aa * 16 + 0], esc[0]);   // (U D0)[aa][0]
  run_layer<false>(a, th_sc, lane);
  run_layer<false>(a, th_sc + 40, lane);
  {
    float4* o4 = (float4*)(state0 + (size_t)blk * 1024) + lane * 8;
#pragma unroll
    for (int q = 0; q < 8; ++q)
      o4[q] = make_float4(a[2 * q].x, a[2 * q].y, a[2 * q + 1].x, a[2 * q + 1].y);
  }
  grid_barrier(bar, 256, lane);

  // ---- phase B: mix M1, select adjoint ----
  mix_load(a, state0, m1row, b, lane);
  run_layer<true>(a, th_sc + 40, lane);
  run_layer<true>(a, th_sc, lane);
  {
    float4* o4 = (float4*)(state1 + (size_t)blk * 1024) + lane * 8;
#pragma unroll
    for (int q = 0; q < 8; ++q)
      o4[q] = make_float4(a[2 * q].x, a[2 * q].y, a[2 * q + 1].x, a[2 * q + 1].y);
  }
  grid_barrier(bar, 512, lane);

  // ---- phase C: mix M2, select forward ----
  mix_load(a, state1, m2row, b, lane);
  run_layer<false>(a, th_sc, lane);
  run_layer<false>(a, th_sc + 40, lane);
  {
    float4* o4 = (float4*)(state0 + (size_t)blk * 1024) + lane * 8;
#pragma unroll
    for (int q = 0; q < 8; ++q)
      o4[q] = make_float4(a[2 * q].x, a[2 * q].y, a[2 * q + 1].x, a[2 * q + 1].y);
  }
  grid_barrier(bar, 768, lane);

  // ---- phase D: mix Mend, qff layer, expvals -> atomic partials ----
  mix_load(a, state0, merow, b, lane);
  run_layer<false>(a, qsc, lane);
  {
    float obs[30];
#pragma unroll
    for (int p = 0; p <= 9; ++p) {
      int i = 9 - p;
      float cr = 0.f, ci = 0.f, zz = 0.f;
      if (p < 4) {
        int m = 1 << p;
#pragma unroll
        for (int r0 = 0; r0 < 16; ++r0) {
          if (!(r0 & m)) {
            float2 A0 = a[r0], A1 = a[r0 | m];
            cr += A0.x * A1.x + A0.y * A1.y;
            ci += A0.x * A1.y - A0.y * A1.x;
            zz += (A0.x * A0.x + A0.y * A0.y) - (A1.x * A1.x + A1.y * A1.y);
          }
        }
      } else {
        int xm = 1 << (p - 4);
        bool up = (lane >> (p - 4)) & 1;
#pragma unroll
        for (int r = 0; r < 16; ++r) {
          float wx = __shfl_xor(a[r].x, xm, 64);
          float wy = __shfl_xor(a[r].y, xm, 64);
          float n2 = a[r].x * a[r].x + a[r].y * a[r].y;
          if (!up) {
            cr += a[r].x * wx + a[r].y * wy;
            ci += a[r].x * wy - a[r].y * wx;
            zz += n2;
          } else {
            zz -= n2;
          }
        }
      }
      obs[i] = 2.f * cr;
      obs[10 + i] = 2.f * ci;
      obs[20 + i] = zz;
    }
#pragma unroll
    for (int j = 0; j < 30; ++j) {
      float v = obs[j];
      for (int off = 32; off; off >>= 1) v += __shfl_down(v, off, 64);
      if (lane == 0) atomicAdd(&sv[b * 30 + j], v);
    }
  }
  grid_barrier(bar, 1024, lane);

  // ---- phase E: out = exps @ W_out^T + b_out ----
  if (blk < 2) {
    int tid = blk * 64 + lane;       // 0..127 = b*8 + o
    int bb = tid >> 3, o = tid & 7;
    float acc = b_out[o];
#pragma unroll
    for (int j = 0; j < 30; ++j) acc += W_out[o * 30 + j] * sv[bb * 30 + j];
    out[tid] = acc;
  }
}

extern "C" void kernel_launch(void* const* d_in, const int* in_sizes, int n_in,
                              void* d_out, int out_size, void* d_ws, size_t ws_size,
                              hipStream_t stream) {
  const float* x     = (const float*)d_in[0];
  const float* W_fp  = (const float*)d_in[1];
  const float* b_fp  = (const float*)d_in[2];
  const float* prep  = (const float*)d_in[3];
  const float* sig   = (const float*)d_in[4];
  const float* qff   = (const float*)d_in[5];
  const float* W_out = (const float*)d_in[6];
  const float* b_out = (const float*)d_in[7];
  float* out = (float*)d_out;

  char* ws = (char*)d_ws;
  const size_t SZ_STATE = 2097152;          // 256 cols * 1024 amps * 8 B
  float2* state0 = (float2*)ws;
  float2* state1 = (float2*)(ws + SZ_STATE);
  float*  sv     = (float*)(ws + 2 * SZ_STATE);           // 16*30 floats
  int*    bar    = (int*)  (ws + 2 * SZ_STATE + 1920);    // barrier counter

  // zero sv (atomic accumulators) + barrier counter; ws is 0xAA-poisoned
  hipMemsetAsync(ws + 2 * SZ_STATE, 0, 1920 + 64, stream);
  k_all<<<256, 64, 0, stream>>>(x, W_fp, b_fp, prep, sig, qff, W_out, b_out,
                                state0, state1, sv, bar, out);
}

// Round 5
// 240.535 us; speedup vs baseline: 1.2030x; 1.2030x over previous
//
#include <hip/hip_runtime.h>
#include <math.h>
#include <utility>

// B=16, T=16, FDIM=64, ODIM=8, NQ=10, NA=4, LAYERS=2, DEGREE=3.
// Single kernel, 256 blocks x 64 threads (1 wave/block). Block blk = b*16+aa
// owns column (b, aa): 1024 amplitudes register-resident, n = lane*16 + r
// (bits [3:0]=r in-thread, [9:4]=lane). Gates on n-bit<4: thread-local;
// n-bit>=4: __shfl_xor butterfly.
// Cross-column deps are per-BATCH (16 blocks), synced by a software barrier:
// relaxed agent-scope polls (no per-poll cache invalidate!) + one
// release/acquire __threadfence pair per barrier. Round-4 lesson: ACQUIRE
// polls emit buffer_inv per iteration -> L2 invalidate storm (239us, 26MB
// HBM fetch). 256 single-wave blocks on 256 CUs are always co-resident.

struct Gate { int ry; int tbit; int cbit; int pidx; };
struct GateTab { Gate g[40]; };

constexpr GateTab make_gates1() {
  GateTab tb{};
  int pos = 0, idx = 0;
  for (int i = 0; i < 10; ++i) { tb.g[pos] = Gate{1, 9 - i, -1, idx}; ++pos; ++idx; }
  for (int i = 9; i >= 0; --i) { tb.g[pos] = Gate{0, 9 - ((i + 1) % 10), 9 - i, idx}; ++pos; ++idx; }
  for (int i = 0; i < 10; ++i) { tb.g[pos] = Gate{1, 9 - i, -1, idx}; ++pos; ++idx; }
  for (int k = 0; k < 10; ++k) {
    int i = (k == 0) ? 9 : (k - 1);
    tb.g[pos] = Gate{0, 9 - ((i + 9) % 10), 9 - i, idx}; ++pos; ++idx;
  }
  return tb;
}
constexpr GateTab GTC = make_gates1();

__device__ __forceinline__ int insert_zero(int v, int p) {
  return ((v >> p) << (p + 1)) | (v & ((1 << p) - 1));
}
__device__ __forceinline__ float2 cmul(float2 A, float2 B) {
  return make_float2(A.x * B.x - A.y * B.y, A.x * B.y + A.y * B.x);
}
__device__ __forceinline__ float2 conj2(float2 A) { return make_float2(A.x, -A.y); }
__device__ __forceinline__ float2 cfma(float2 A, float2 B, float2 acc) {
  acc.x += A.x * B.x - A.y * B.y;
  acc.y += A.x * B.y + A.y * B.x;
  return acc;
}

// ---- software per-batch barrier (fence-based synchronization) ----
// release fence + relaxed arrive; relaxed polls; acquire fence after exit.
__device__ __forceinline__ void bar_arrive(int* cnt, int lane) {
  __threadfence();                                   // release my stores (wbl2)
  if (lane == 0)
    __hip_atomic_fetch_add(cnt, 1, __ATOMIC_RELAXED, __HIP_MEMORY_SCOPE_AGENT);
}
__device__ __forceinline__ void bar_wait(int* cnt, int target, int lane) {
  if (lane == 0) {
    while (__hip_atomic_load(cnt, __ATOMIC_RELAXED, __HIP_MEMORY_SCOPE_AGENT) < target)
      __builtin_amdgcn_s_sleep(8);
  }
  __threadfence();                                   // acquire others' stores (inv)
}

// ---------------- register/shuffle gate engine ----------------
template<int P>
__device__ __forceinline__ void ry_gate(float2 (&a)[16], float c, float s, int lane) {
  if constexpr (P < 4) {
    constexpr int m = 1 << P;
#pragma unroll
    for (int r0 = 0; r0 < 16; ++r0) {
      if (!(r0 & m)) {
        int r1 = r0 | m;
        float2 a0 = a[r0], a1 = a[r1];
        a[r0] = make_float2(c * a0.x - s * a1.x, c * a0.y - s * a1.y);
        a[r1] = make_float2(s * a0.x + c * a1.x, s * a0.y + c * a1.y);
      }
    }
  } else {
    constexpr int xm = 1 << (P - 4);
    bool up = (lane >> (P - 4)) & 1;
    float sg = up ? s : -s;
#pragma unroll
    for (int r = 0; r < 16; ++r) {
      float wx = __shfl_xor(a[r].x, xm, 64);
      float wy = __shfl_xor(a[r].y, xm, 64);
      a[r].x = c * a[r].x + sg * wx;
      a[r].y = c * a[r].y + sg * wy;
    }
  }
}

template<int P, int Q>
__device__ __forceinline__ void crx_gate(float2 (&a)[16], float c, float s, int lane) {
  if constexpr (P < 4) {
    constexpr int m = 1 << P;
#pragma unroll
    for (int r0 = 0; r0 < 16; ++r0) {
      if (!(r0 & m)) {
        int r1 = r0 | m;
        bool act;
        if constexpr (Q < 4) act = (r0 >> Q) & 1;
        else act = (lane >> (Q - 4)) & 1;
        if (act) {
          float2 a0 = a[r0], a1 = a[r1];
          a[r0] = make_float2(c * a0.x + s * a1.y, c * a0.y - s * a1.x);
          a[r1] = make_float2(c * a1.x + s * a0.y, c * a1.y - s * a0.x);
        }
      }
    }
  } else {
    constexpr int xm = 1 << (P - 4);
#pragma unroll
    for (int r = 0; r < 16; ++r) {
      float wx = __shfl_xor(a[r].x, xm, 64);
      float wy = __shfl_xor(a[r].y, xm, 64);
      bool act;
      if constexpr (Q < 4) act = (r >> Q) & 1;
      else act = (lane >> (Q - 4)) & 1;
      if (act) {
        float nx = c * a[r].x + s * wy;
        float ny = c * a[r].y - s * wx;
        a[r].x = nx; a[r].y = ny;
      }
    }
  }
}

template<bool ADJ, int G>
__device__ __forceinline__ void one_gate(float2 (&a)[16], const float2* sc, int lane) {
  constexpr Gate g = GTC.g[ADJ ? (39 - G) : G];
  float2 scv = sc[g.pidx];          // (sin(th/2), cos(th/2)), wave-uniform LDS read
  float s = ADJ ? -scv.x : scv.x;
  float c = scv.y;
  if constexpr (g.ry != 0) ry_gate<g.tbit>(a, c, s, lane);
  else crx_gate<g.tbit, g.cbit>(a, c, s, lane);
}

template<bool ADJ, int... I>
__device__ __forceinline__ void run_layer_impl(float2 (&a)[16], const float2* sc,
                                               int lane, std::integer_sequence<int, I...>) {
  (one_gate<ADJ, I>(a, sc, lane), ...);
}
template<bool ADJ>
__device__ __forceinline__ void run_layer(float2 (&a)[16], const float2* sc, int lane) {
  run_layer_impl<ADJ>(a, sc, lane, std::make_integer_sequence<int, 40>{});
}

// a[r] = sum_ap Mrow[ap] * src[b][ap][lane*16+r]   (Mrow in LDS)
__device__ __forceinline__ void mix_load(float2 (&a)[16], const float2* __restrict__ src,
                                         const float2* Mrow, int b, int lane) {
#pragma unroll
  for (int r = 0; r < 16; ++r) a[r] = make_float2(0.f, 0.f);
#pragma unroll
  for (int ap = 0; ap < 16; ++ap) {
    float2 m = Mrow[ap];
    const float4* col4 = (const float4*)(src + (size_t)(b * 16 + ap) * 1024) + lane * 8;
#pragma unroll
    for (int q = 0; q < 8; ++q) {
      float4 v = col4[q];
      a[2 * q].x     += m.x * v.x - m.y * v.y;
      a[2 * q].y     += m.x * v.y + m.y * v.x;
      a[2 * q + 1].x += m.x * v.z - m.y * v.w;
      a[2 * q + 1].y += m.x * v.w + m.y * v.z;
    }
  }
}

__global__ __launch_bounds__(64)
void k_all(const float* __restrict__ x, const float* __restrict__ W_fp,
           const float* __restrict__ b_fp, const float* __restrict__ prep,
           const float* __restrict__ sig, const float* __restrict__ qff,
           const float* __restrict__ W_out, const float* __restrict__ b_out,
           float2* __restrict__ state0, float2* __restrict__ state1,
           float* __restrict__ svp, int* __restrict__ bar,
           float* __restrict__ out) {
  int blk = blockIdx.x, lane = threadIdx.x;   // blk = b*16 + aa
  int b = blk >> 4, aa = blk & 15;
  int* bcnt = bar + b * 16;                   // per-batch counter, 64B stride

  __shared__ __align__(16) float h[64];
  __shared__ float2 th_sc[80];
  __shared__ float2 qsc[40];
  __shared__ float2 psc[32];
  __shared__ float2 esc[4];       // e^{i sig[k]} as (re, im)
  __shared__ float2 U[256];       // U[row*16 + col]
  __shared__ float2 m1row[16], m2row[16], merow[16];
  __shared__ float svtot[30];

  // ---- phase 0: block-local precompute ----
  {
    int k = lane >> 1;
    float div = expf(-(float)(2 * k) * (logf(10000.f) / 64.f));
    float ang = (float)aa * div;
    float pe = (lane & 1) ? cosf(ang) : sinf(ang);
    h[lane] = x[(b * 64 + lane) * 16 + aa] + pe;
  }
  if (lane < 40) {
    float s, c;
    sincosf(0.5f * qff[lane], &s, &c);
    qsc[lane] = make_float2(s, c);
  }
  if (lane < 32) {
    float s, c;
    sincosf(0.5f * prep[lane], &s, &c);
    psc[lane] = make_float2(s, c);
  }
  if (lane < 4) {
    float s, c;
    sincosf(sig[lane], &s, &c);
    esc[lane] = make_float2(c, s);
  }
#pragma unroll
  for (int i = lane; i < 256; i += 64)
    U[i] = make_float2((i >> 4) == (i & 15) ? 1.f : 0.f, 0.f);
  __syncthreads();

  // feature-map angles for this column (t = aa)
  for (int r = lane; r < 80; r += 64) {
    float acc = b_fp[r];
    const float4* w4 = (const float4*)(W_fp + r * 64);
    const float4* h4 = (const float4*)h;
#pragma unroll
    for (int q = 0; q < 16; ++q) {
      float4 wv = w4[q];
      float4 hv = h4[q];
      acc += hv.x * wv.x + hv.y * wv.y + hv.z * wv.z + hv.w * wv.w;
    }
    float sg = 1.f / (1.f + expf(-acc));
    float s, c;
    sincosf(sg * 3.14159265358979323846f, &s, &c);   // theta/2
    th_sc[r] = make_float2(s, c);
  }

  // build U_prep (16x16) in LDS, single wave
  for (int ly = 0; ly < 4; ++ly) {
    for (int qi = 0; qi < 4; ++qi) {
      int p = 3 - qi;
      {
        float2 sc = psc[ly * 8 + qi * 2 + 0];
        float s = sc.x, c = sc.y;
#pragma unroll
        for (int u = 0; u < 2; ++u) {
          int idx = lane + 64 * u;
          int j = idx & 15, pp = idx >> 4;
          int a0 = insert_zero(pp, p), a1 = a0 | (1 << p);
          float2 u0 = U[a0 * 16 + j], u1 = U[a1 * 16 + j];
          U[a0 * 16 + j] = make_float2(c * u0.x - s * u1.x, c * u0.y - s * u1.y);
          U[a1 * 16 + j] = make_float2(s * u0.x + c * u1.x, s * u0.y + c * u1.y);
        }
      }
      __syncthreads();
      {
        float2 sc = psc[ly * 8 + qi * 2 + 1];
        float s = sc.x, c = sc.y;
#pragma unroll
        for (int u = 0; u < 2; ++u) {
          int idx = lane + 64 * u;
          int j = idx & 15, pp = idx >> 4;
          int a0 = insert_zero(pp, p), a1 = a0 | (1 << p);
          float2 u0 = U[a0 * 16 + j], u1 = U[a1 * 16 + j];
          U[a0 * 16 + j] = make_float2(c * u0.x + s * u0.y, c * u0.y - s * u0.x);
          U[a1 * 16 + j] = make_float2(c * u1.x - s * u1.y, c * u1.y + s * u1.x);
        }
      }
      __syncthreads();
    }
    for (int i = 0; i < 3; ++i) {
      int pc = 3 - i, pt = 2 - i;
      {
        int j = lane & 15, pp = lane >> 4;
        int m = insert_zero(pp, pt);
        m = insert_zero(m, pc);
        int a0 = m | (1 << pc), a1 = a0 | (1 << pt);
        float2 t0 = U[a0 * 16 + j], t1 = U[a1 * 16 + j];
        U[a0 * 16 + j] = t1;
        U[a1 * 16 + j] = t0;
      }
      __syncthreads();
    }
  }

  // extract row aa of M1 = U D1 U^dag, M2 = U D2 U^dag, Mend = D3 U^dag
  if (lane < 16) {
    int ap = lane;
    float2 e1 = esc[1], e2 = esc[2], e3 = esc[3];
    float2 acc1 = make_float2(0.f, 0.f), acc2 = make_float2(0.f, 0.f);
    for (int c = 0; c < 16; ++c) {
      float2 t = cmul(U[aa * 16 + c], conj2(U[ap * 16 + c]));
      acc1 = cfma(t, (c == 0) ? e1 : conj2(e1), acc1);
      acc2 = cfma(t, (c == 0) ? e2 : conj2(e2), acc2);
    }
    m1row[ap] = acc1;
    m2row[ap] = acc2;
    float2 v3 = (aa == 0) ? e3 : conj2(e3);
    merow[ap] = cmul(v3, conj2(U[ap * 16 + aa]));
  }
  __syncthreads();

  // ---- phase A: init |0> -> prepare column aa, select forward ----
  float2 a[16];
#pragma unroll
  for (int r = 0; r < 16; ++r) a[r] = make_float2(0.f, 0.f);
  if (lane == 0) a[0] = cmul(U[aa * 16 + 0], esc[0]);   // (U D0)[aa][0]
  run_layer<false>(a, th_sc, lane);
  run_layer<false>(a, th_sc + 40, lane);
  {
    float4* o4 = (float4*)(state0 + (size_t)blk * 1024) + lane * 8;
#pragma unroll
    for (int q = 0; q < 8; ++q)
      o4[q] = make_float4(a[2 * q].x, a[2 * q].y, a[2 * q + 1].x, a[2 * q + 1].y);
  }
  bar_arrive(bcnt, lane);
  bar_wait(bcnt, 16, lane);

  // ---- phase B: mix M1, select adjoint ----
  mix_load(a, state0, m1row, b, lane);
  run_layer<true>(a, th_sc + 40, lane);
  run_layer<true>(a, th_sc, lane);
  {
    float4* o4 = (float4*)(state1 + (size_t)blk * 1024) + lane * 8;
#pragma unroll
    for (int q = 0; q < 8; ++q)
      o4[q] = make_float4(a[2 * q].x, a[2 * q].y, a[2 * q + 1].x, a[2 * q + 1].y);
  }
  bar_arrive(bcnt, lane);
  bar_wait(bcnt, 32, lane);

  // ---- phase C: mix M2, select forward ----
  mix_load(a, state1, m2row, b, lane);
  run_layer<false>(a, th_sc, lane);
  run_layer<false>(a, th_sc + 40, lane);
  {
    float4* o4 = (float4*)(state0 + (size_t)blk * 1024) + lane * 8;
#pragma unroll
    for (int q = 0; q < 8; ++q)
      o4[q] = make_float4(a[2 * q].x, a[2 * q].y, a[2 * q + 1].x, a[2 * q + 1].y);
  }
  bar_arrive(bcnt, lane);
  bar_wait(bcnt, 48, lane);

  // ---- phase D: mix Mend, qff layer, expvals -> svp[blk][30] ----
  mix_load(a, state0, merow, b, lane);
  run_layer<false>(a, qsc, lane);
  {
    float obs[30];
#pragma unroll
    for (int p = 0; p <= 9; ++p) {
      int i = 9 - p;
      float cr = 0.f, ci = 0.f, zz = 0.f;
      if (p < 4) {
        int m = 1 << p;
#pragma unroll
        for (int r0 = 0; r0 < 16; ++r0) {
          if (!(r0 & m)) {
            float2 A0 = a[r0], A1 = a[r0 | m];
            cr += A0.x * A1.x + A0.y * A1.y;
            ci += A0.x * A1.y - A0.y * A1.x;
            zz += (A0.x * A0.x + A0.y * A0.y) - (A1.x * A1.x + A1.y * A1.y);
          }
        }
      } else {
        int xm = 1 << (p - 4);
        bool up = (lane >> (p - 4)) & 1;
#pragma unroll
        for (int r = 0; r < 16; ++r) {
          float wx = __shfl_xor(a[r].x, xm, 64);
          float wy = __shfl_xor(a[r].y, xm, 64);
          float n2 = a[r].x * a[r].x + a[r].y * a[r].y;
          if (!up) {
            cr += a[r].x * wx + a[r].y * wy;
            ci += a[r].x * wy - a[r].y * wx;
            zz += n2;
          } else {
            zz -= n2;
          }
        }
      }
      obs[i] = 2.f * cr;
      obs[10 + i] = 2.f * ci;
      obs[20 + i] = zz;
    }
#pragma unroll
    for (int j = 0; j < 30; ++j) {
      float v = obs[j];
      for (int off = 32; off; off >>= 1) v += __shfl_down(v, off, 64);
      if (lane == 0) svp[blk * 32 + j] = v;
    }
  }
  bar_arrive(bcnt, lane);

  // ---- phase E: block (b,0) reduces batch partials and writes out ----
  if (aa == 0) {
    bar_wait(bcnt, 64, lane);
    if (lane < 30) {
      float tot = 0.f;
#pragma unroll
      for (int k = 0; k < 16; ++k) tot += svp[(b * 16 + k) * 32 + lane];
      svtot[lane] = tot;
    }
    __syncthreads();
    if (lane < 8) {
      float acc = b_out[lane];
#pragma unroll
      for (int j = 0; j < 30; ++j) acc += W_out[lane * 30 + j] * svtot[j];
      out[b * 8 + lane] = acc;
    }
  }
}

extern "C" void kernel_launch(void* const* d_in, const int* in_sizes, int n_in,
                              void* d_out, int out_size, void* d_ws, size_t ws_size,
                              hipStream_t stream) {
  const float* x     = (const float*)d_in[0];
  const float* W_fp  = (const float*)d_in[1];
  const float* b_fp  = (const float*)d_in[2];
  const float* prep  = (const float*)d_in[3];
  const float* sig   = (const float*)d_in[4];
  const float* qff   = (const float*)d_in[5];
  const float* W_out = (const float*)d_in[6];
  const float* b_out = (const float*)d_in[7];
  float* out = (float*)d_out;

  char* ws = (char*)d_ws;
  const size_t SZ_STATE = 2097152;          // 256 cols * 1024 amps * 8 B
  float2* state0 = (float2*)ws;
  float2* state1 = (float2*)(ws + SZ_STATE);
  int*    bar    = (int*)  (ws + 2 * SZ_STATE);            // 16 counters, 64B stride
  float*  svp    = (float*)(ws + 2 * SZ_STATE + 1024);     // 256*32 floats

  // zero the 16 per-batch barrier counters (ws is 0xAA-poisoned each call)
  hipMemsetAsync(bar, 0, 1024, stream);
  k_all<<<256, 64, 0, stream>>>(x, W_fp, b_fp, prep, sig, qff, W_out, b_out,
                                state0, state1, svp, bar, out);
}

// Round 6
// 221.163 us; speedup vs baseline: 1.3084x; 1.0876x over previous
//
#include <hip/hip_runtime.h>
#include <math.h>
#include <utility>

// B=16, T=16, FDIM=64, ODIM=8, NQ=10, NA=4, LAYERS=2, DEGREE=3.
// Single kernel, 256 blocks x 64 threads (1 wave/block). Block blk = aa*16+b
// (b = blk&15 -> all 16 columns of a batch share blk%8 => same XCD: mixes and
// barriers are XCD-local). Column (b,aa): 1024 amplitudes register-resident,
// n = lane*16 + r. Gates on n-bit<4: thread-local; n-bit>=4: __shfl_xor
// butterfly with ALL 32 shuffles issued before any consumer (round-5 lesson:
// interleaved shuffle+FMA exposed ~50cyc bpermute latency 16x per gate with
// 1 wave/SIMD -> ~1500cyc/gate).
// Per-batch software barrier: relaxed agent-scope polls + one release/acquire
// threadfence pair (round-4 lesson: ACQUIRE polls = buffer_inv storm).

struct Gate { int ry; int tbit; int cbit; int pidx; };
struct GateTab { Gate g[40]; };

constexpr GateTab make_gates1() {
  GateTab tb{};
  int pos = 0, idx = 0;
  for (int i = 0; i < 10; ++i) { tb.g[pos] = Gate{1, 9 - i, -1, idx}; ++pos; ++idx; }
  for (int i = 9; i >= 0; --i) { tb.g[pos] = Gate{0, 9 - ((i + 1) % 10), 9 - i, idx}; ++pos; ++idx; }
  for (int i = 0; i < 10; ++i) { tb.g[pos] = Gate{1, 9 - i, -1, idx}; ++pos; ++idx; }
  for (int k = 0; k < 10; ++k) {
    int i = (k == 0) ? 9 : (k - 1);
    tb.g[pos] = Gate{0, 9 - ((i + 9) % 10), 9 - i, idx}; ++pos; ++idx;
  }
  return tb;
}
constexpr GateTab GTC = make_gates1();

__device__ __forceinline__ int insert_zero(int v, int p) {
  return ((v >> p) << (p + 1)) | (v & ((1 << p) - 1));
}
__device__ __forceinline__ float2 cmul(float2 A, float2 B) {
  return make_float2(A.x * B.x - A.y * B.y, A.x * B.y + A.y * B.x);
}
__device__ __forceinline__ float2 conj2(float2 A) { return make_float2(A.x, -A.y); }
__device__ __forceinline__ float2 cfma(float2 A, float2 B, float2 acc) {
  acc.x += A.x * B.x - A.y * B.y;
  acc.y += A.x * B.y + A.y * B.x;
  return acc;
}

// ---- software per-batch barrier (fence-based synchronization) ----
__device__ __forceinline__ void bar_arrive(int* cnt, int lane) {
  __threadfence();                                   // release my stores
  if (lane == 0)
    __hip_atomic_fetch_add(cnt, 1, __ATOMIC_RELAXED, __HIP_MEMORY_SCOPE_AGENT);
}
__device__ __forceinline__ void bar_wait(int* cnt, int target, int lane) {
  if (lane == 0) {
    while (__hip_atomic_load(cnt, __ATOMIC_RELAXED, __HIP_MEMORY_SCOPE_AGENT) < target)
      __builtin_amdgcn_s_sleep(8);
  }
  __threadfence();                                   // acquire others' stores
}

// ---------------- register/shuffle gate engine ----------------
template<int P>
__device__ __forceinline__ void ry_gate(float2 (&a)[16], float c, float s, int lane) {
  if constexpr (P < 4) {
    constexpr int m = 1 << P;
#pragma unroll
    for (int r0 = 0; r0 < 16; ++r0) {
      if (!(r0 & m)) {
        int r1 = r0 | m;
        float2 a0 = a[r0], a1 = a[r1];
        a[r0] = make_float2(c * a0.x - s * a1.x, c * a0.y - s * a1.y);
        a[r1] = make_float2(s * a0.x + c * a1.x, s * a0.y + c * a1.y);
      }
    }
  } else {
    constexpr int xm = 1 << (P - 4);
    bool up = (lane >> (P - 4)) & 1;
    float sg = up ? s : -s;
    float wx[16], wy[16];
#pragma unroll
    for (int r = 0; r < 16; ++r) {      // all 32 shuffles issued back-to-back
      wx[r] = __shfl_xor(a[r].x, xm, 64);
      wy[r] = __shfl_xor(a[r].y, xm, 64);
    }
#pragma unroll
    for (int r = 0; r < 16; ++r) {
      a[r].x = c * a[r].x + sg * wx[r];
      a[r].y = c * a[r].y + sg * wy[r];
    }
  }
}

template<int P, int Q>
__device__ __forceinline__ void crx_gate(float2 (&a)[16], float c, float s, int lane) {
  if constexpr (P < 4) {
    constexpr int m = 1 << P;
#pragma unroll
    for (int r0 = 0; r0 < 16; ++r0) {
      if (!(r0 & m)) {
        int r1 = r0 | m;
        bool act;
        if constexpr (Q < 4) act = (r0 >> Q) & 1;
        else act = (lane >> (Q - 4)) & 1;
        if (act) {
          float2 a0 = a[r0], a1 = a[r1];
          a[r0] = make_float2(c * a0.x + s * a1.y, c * a0.y - s * a1.x);
          a[r1] = make_float2(c * a1.x + s * a0.y, c * a1.y - s * a0.x);
        }
      }
    }
  } else {
    constexpr int xm = 1 << (P - 4);
    float wx[16], wy[16];
#pragma unroll
    for (int r = 0; r < 16; ++r) {      // all 32 shuffles issued back-to-back
      wx[r] = __shfl_xor(a[r].x, xm, 64);
      wy[r] = __shfl_xor(a[r].y, xm, 64);
    }
#pragma unroll
    for (int r = 0; r < 16; ++r) {
      bool act;
      if constexpr (Q < 4) act = (r >> Q) & 1;
      else act = (lane >> (Q - 4)) & 1;
      if (act) {
        float nx = c * a[r].x + s * wy[r];
        float ny = c * a[r].y - s * wx[r];
        a[r].x = nx; a[r].y = ny;
      }
    }
  }
}

template<bool ADJ, int G>
__device__ __forceinline__ void one_gate(float2 (&a)[16], const float2* sc, int lane) {
  constexpr Gate g = GTC.g[ADJ ? (39 - G) : G];
  float2 scv = sc[g.pidx];          // (sin(th/2), cos(th/2)), wave-uniform LDS read
  float s = ADJ ? -scv.x : scv.x;
  float c = scv.y;
  if constexpr (g.ry != 0) ry_gate<g.tbit>(a, c, s, lane);
  else crx_gate<g.tbit, g.cbit>(a, c, s, lane);
}

template<bool ADJ, int... I>
__device__ __forceinline__ void run_layer_impl(float2 (&a)[16], const float2* sc,
                                               int lane, std::integer_sequence<int, I...>) {
  (one_gate<ADJ, I>(a, sc, lane), ...);
}
template<bool ADJ>
__device__ __forceinline__ void run_layer(float2 (&a)[16], const float2* sc, int lane) {
  run_layer_impl<ADJ>(a, sc, lane, std::make_integer_sequence<int, 40>{});
}

// a[r] = sum_ap Mrow[ap] * src[b][ap][lane*16+r]   (Mrow in LDS)
__device__ __forceinline__ void mix_load(float2 (&a)[16], const float2* __restrict__ src,
                                         const float2* Mrow, int b, int lane) {
#pragma unroll
  for (int r = 0; r < 16; ++r) a[r] = make_float2(0.f, 0.f);
#pragma unroll
  for (int ap = 0; ap < 16; ++ap) {
    float2 m = Mrow[ap];
    const float4* col4 = (const float4*)(src + (size_t)(b * 16 + ap) * 1024) + lane * 8;
#pragma unroll
    for (int q = 0; q < 8; ++q) {
      float4 v = col4[q];
      a[2 * q].x     += m.x * v.x - m.y * v.y;
      a[2 * q].y     += m.x * v.y + m.y * v.x;
      a[2 * q + 1].x += m.x * v.z - m.y * v.w;
      a[2 * q + 1].y += m.x * v.w + m.y * v.z;
    }
  }
}

__global__ __launch_bounds__(64)
void k_all(const float* __restrict__ x, const float* __restrict__ W_fp,
           const float* __restrict__ b_fp, const float* __restrict__ prep,
           const float* __restrict__ sig, const float* __restrict__ qff,
           const float* __restrict__ W_out, const float* __restrict__ b_out,
           float2* __restrict__ state0, float2* __restrict__ state1,
           float* __restrict__ svp, int* __restrict__ bar,
           float* __restrict__ out) {
  int blk = blockIdx.x, lane = threadIdx.x;   // blk = aa*16 + b (XCD-local batches)
  int b = blk & 15, aa = blk >> 4;
  int col = b * 16 + aa;                      // state column index
  int* bcnt = bar + b * 16;                   // per-batch counter, 64B stride

  __shared__ __align__(16) float h[64];
  __shared__ float2 th_sc[80];
  __shared__ float2 qsc[40];
  __shared__ float2 psc[32];
  __shared__ float2 esc[4];       // e^{i sig[k]} as (re, im)
  __shared__ float2 U[256];       // U[row*16 + col]
  __shared__ float2 m1row[16], m2row[16], merow[16];
  __shared__ float svtot[30];

  // ---- phase 0: block-local precompute ----
  {
    int k = lane >> 1;
    float div = expf(-(float)(2 * k) * (logf(10000.f) / 64.f));
    float ang = (float)aa * div;                 // t = aa
    float pe = (lane & 1) ? cosf(ang) : sinf(ang);
    h[lane] = x[(b * 64 + lane) * 16 + aa] + pe;
  }
  if (lane < 40) {
    float s, c;
    sincosf(0.5f * qff[lane], &s, &c);
    qsc[lane] = make_float2(s, c);
  }
  if (lane < 32) {
    float s, c;
    sincosf(0.5f * prep[lane], &s, &c);
    psc[lane] = make_float2(s, c);
  }
  if (lane < 4) {
    float s, c;
    sincosf(sig[lane], &s, &c);
    esc[lane] = make_float2(c, s);
  }
#pragma unroll
  for (int i = lane; i < 256; i += 64)
    U[i] = make_float2((i >> 4) == (i & 15) ? 1.f : 0.f, 0.f);
  __syncthreads();

  // feature-map angles for this column (t = aa)
  for (int r = lane; r < 80; r += 64) {
    float acc = b_fp[r];
    const float4* w4 = (const float4*)(W_fp + r * 64);
    const float4* h4 = (const float4*)h;
#pragma unroll
    for (int q = 0; q < 16; ++q) {
      float4 wv = w4[q];
      float4 hv = h4[q];
      acc += hv.x * wv.x + hv.y * wv.y + hv.z * wv.z + hv.w * wv.w;
    }
    float sg = 1.f / (1.f + expf(-acc));
    float s, c;
    sincosf(sg * 3.14159265358979323846f, &s, &c);   // theta/2
    th_sc[r] = make_float2(s, c);
  }

  // build U_prep (16x16) in LDS, single wave
  for (int ly = 0; ly < 4; ++ly) {
    for (int qi = 0; qi < 4; ++qi) {
      int p = 3 - qi;
      {
        float2 sc = psc[ly * 8 + qi * 2 + 0];
        float s = sc.x, c = sc.y;
#pragma unroll
        for (int u = 0; u < 2; ++u) {
          int idx = lane + 64 * u;
          int j = idx & 15, pp = idx >> 4;
          int a0 = insert_zero(pp, p), a1 = a0 | (1 << p);
          float2 u0 = U[a0 * 16 + j], u1 = U[a1 * 16 + j];
          U[a0 * 16 + j] = make_float2(c * u0.x - s * u1.x, c * u0.y - s * u1.y);
          U[a1 * 16 + j] = make_float2(s * u0.x + c * u1.x, s * u0.y + c * u1.y);
        }
      }
      __syncthreads();
      {
        float2 sc = psc[ly * 8 + qi * 2 + 1];
        float s = sc.x, c = sc.y;
#pragma unroll
        for (int u = 0; u < 2; ++u) {
          int idx = lane + 64 * u;
          int j = idx & 15, pp = idx >> 4;
          int a0 = insert_zero(pp, p), a1 = a0 | (1 << p);
          float2 u0 = U[a0 * 16 + j], u1 = U[a1 * 16 + j];
          U[a0 * 16 + j] = make_float2(c * u0.x + s * u0.y, c * u0.y - s * u0.x);
          U[a1 * 16 + j] = make_float2(c * u1.x - s * u1.y, c * u1.y + s * u1.x);
        }
      }
      __syncthreads();
    }
    for (int i = 0; i < 3; ++i) {
      int pc = 3 - i, pt = 2 - i;
      {
        int j = lane & 15, pp = lane >> 4;
        int m = insert_zero(pp, pt);
        m = insert_zero(m, pc);
        int a0 = m | (1 << pc), a1 = a0 | (1 << pt);
        float2 t0 = U[a0 * 16 + j], t1 = U[a1 * 16 + j];
        U[a0 * 16 + j] = t1;
        U[a1 * 16 + j] = t0;
      }
      __syncthreads();
    }
  }

  // extract row aa of M1 = U D1 U^dag, M2 = U D2 U^dag, Mend = D3 U^dag
  if (lane < 16) {
    int ap = lane;
    float2 e1 = esc[1], e2 = esc[2], e3 = esc[3];
    float2 acc1 = make_float2(0.f, 0.f), acc2 = make_float2(0.f, 0.f);
    for (int c = 0; c < 16; ++c) {
      float2 t = cmul(U[aa * 16 + c], conj2(U[ap * 16 + c]));
      acc1 = cfma(t, (c == 0) ? e1 : conj2(e1), acc1);
      acc2 = cfma(t, (c == 0) ? e2 : conj2(e2), acc2);
    }
    m1row[ap] = acc1;
    m2row[ap] = acc2;
    float2 v3 = (aa == 0) ? e3 : conj2(e3);
    merow[ap] = cmul(v3, conj2(U[ap * 16 + aa]));
  }
  __syncthreads();

  // ---- phase A: init |0> -> prepare column aa, select forward ----
  float2 a[16];
#pragma unroll
  for (int r = 0; r < 16; ++r) a[r] = make_float2(0.f, 0.f);
  if (lane == 0) a[0] = cmul(U[aa * 16 + 0], esc[0]);   // (U D0)[aa][0]
  run_layer<false>(a, th_sc, lane);
  run_layer<false>(a, th_sc + 40, lane);
  {
    float4* o4 = (float4*)(state0 + (size_t)col * 1024) + lane * 8;
#pragma unroll
    for (int q = 0; q < 8; ++q)
      o4[q] = make_float4(a[2 * q].x, a[2 * q].y, a[2 * q + 1].x, a[2 * q + 1].y);
  }
  bar_arrive(bcnt, lane);
  bar_wait(bcnt, 16, lane);

  // ---- phase B: mix M1, select adjoint ----
  mix_load(a, state0, m1row, b, lane);
  run_layer<true>(a, th_sc + 40, lane);
  run_layer<true>(a, th_sc, lane);
  {
    float4* o4 = (float4*)(state1 + (size_t)col * 1024) + lane * 8;
#pragma unroll
    for (int q = 0; q < 8; ++q)
      o4[q] = make_float4(a[2 * q].x, a[2 * q].y, a[2 * q + 1].x, a[2 * q + 1].y);
  }
  bar_arrive(bcnt, lane);
  bar_wait(bcnt, 32, lane);

  // ---- phase C: mix M2, select forward ----
  mix_load(a, state1, m2row, b, lane);
  run_layer<false>(a, th_sc, lane);
  run_layer<false>(a, th_sc + 40, lane);
  {
    float4* o4 = (float4*)(state0 + (size_t)col * 1024) + lane * 8;
#pragma unroll
    for (int q = 0; q < 8; ++q)
      o4[q] = make_float4(a[2 * q].x, a[2 * q].y, a[2 * q + 1].x, a[2 * q + 1].y);
  }
  bar_arrive(bcnt, lane);
  bar_wait(bcnt, 48, lane);

  // ---- phase D: mix Mend, qff layer, expvals -> svp[col][30] ----
  mix_load(a, state0, merow, b, lane);
  run_layer<false>(a, qsc, lane);
  {
    float obs[30];
#pragma unroll
    for (int p = 0; p <= 9; ++p) {
      int i = 9 - p;
      float cr = 0.f, ci = 0.f, zz = 0.f;
      if (p < 4) {
        int m = 1 << p;
#pragma unroll
        for (int r0 = 0; r0 < 16; ++r0) {
          if (!(r0 & m)) {
            float2 A0 = a[r0], A1 = a[r0 | m];
            cr += A0.x * A1.x + A0.y * A1.y;
            ci += A0.x * A1.y - A0.y * A1.x;
            zz += (A0.x * A0.x + A0.y * A0.y) - (A1.x * A1.x + A1.y * A1.y);
          }
        }
      } else {
        int xm = 1 << (p - 4);
        bool up = (lane >> (p - 4)) & 1;
        float wx[16], wy[16];
#pragma unroll
        for (int r = 0; r < 16; ++r) {
          wx[r] = __shfl_xor(a[r].x, xm, 64);
          wy[r] = __shfl_xor(a[r].y, xm, 64);
        }
#pragma unroll
        for (int r = 0; r < 16; ++r) {
          float n2 = a[r].x * a[r].x + a[r].y * a[r].y;
          if (!up) {
            cr += a[r].x * wx[r] + a[r].y * wy[r];
            ci += a[r].x * wy[r] - a[r].y * wx[r];
            zz += n2;
          } else {
            zz -= n2;
          }
        }
      }
      obs[i] = 2.f * cr;
      obs[10 + i] = 2.f * ci;
      obs[20 + i] = zz;
    }
#pragma unroll
    for (int j = 0; j < 30; ++j) {
      float v = obs[j];
      for (int off = 32; off; off >>= 1) v += __shfl_down(v, off, 64);
      if (lane == 0) svp[col * 32 + j] = v;
    }
  }
  bar_arrive(bcnt, lane);

  // ---- phase E: block (aa=0) of each batch reduces partials, writes out ----
  if (aa == 0) {
    bar_wait(bcnt, 64, lane);
    if (lane < 30) {
      float tot = 0.f;
#pragma unroll
      for (int k = 0; k < 16; ++k) tot += svp[(b * 16 + k) * 32 + lane];
      svtot[lane] = tot;
    }
    __syncthreads();
    if (lane < 8) {
      float acc = b_out[lane];
#pragma unroll
      for (int j = 0; j < 30; ++j) acc += W_out[lane * 30 + j] * svtot[j];
      out[b * 8 + lane] = acc;
    }
  }
}

extern "C" void kernel_launch(void* const* d_in, const int* in_sizes, int n_in,
                              void* d_out, int out_size, void* d_ws, size_t ws_size,
                              hipStream_t stream) {
  const float* x     = (const float*)d_in[0];
  const float* W_fp  = (const float*)d_in[1];
  const float* b_fp  = (const float*)d_in[2];
  const float* prep  = (const float*)d_in[3];
  const float* sig   = (const float*)d_in[4];
  const float* qff   = (const float*)d_in[5];
  const float* W_out = (const float*)d_in[6];
  const float* b_out = (const float*)d_in[7];
  float* out = (float*)d_out;

  char* ws = (char*)d_ws;
  const size_t SZ_STATE = 2097152;          // 256 cols * 1024 amps * 8 B
  float2* state0 = (float2*)ws;
  float2* state1 = (float2*)(ws + SZ_STATE);
  int*    bar    = (int*)  (ws + 2 * SZ_STATE);            // 16 counters, 64B stride
  float*  svp    = (float*)(ws + 2 * SZ_STATE + 1024);     // 256*32 floats

  // zero the 16 per-batch barrier counters (ws is 0xAA-poisoned each call)
  hipMemsetAsync(bar, 0, 1024, stream);
  k_all<<<256, 64, 0, stream>>>(x, W_fp, b_fp, prep, sig, qff, W_out, b_out,
                                state0, state1, svp, bar, out);
}